// Round 5
// baseline (535.546 us; speedup 1.0000x reference)
//
#include <hip/hip_runtime.h>

#define BB 2
#define LL 512
#define HH 128
#define NH 8
#define SP_STRIDE 9   // pad 8 heads to 9 -> odd stride, conflict-free
#define KHALF 256     // ki rows per block (2-way flash split)

typedef float f32x4 __attribute__((ext_vector_type(4)));

// K1: q = x@Wq+bq ; kp = x@Wk+bk+abs_pos_k ; vp = x@Wv+bv+abs_pos_v
// 512 blocks x 2 rows (2 blocks/CU) -- was 256 blocks (1/CU).
__global__ __launch_bounds__(128) void qkv_proj_kernel(
    const float* __restrict__ x,
    const float* __restrict__ abs_pos_k,
    const float* __restrict__ abs_pos_v,
    const float* __restrict__ Wq, const float* __restrict__ bq,
    const float* __restrict__ Wk, const float* __restrict__ bk,
    const float* __restrict__ Wv, const float* __restrict__ bv,
    float* __restrict__ q, float* __restrict__ kp, float* __restrict__ vp)
{
    const int r0 = blockIdx.x * 2;
    const int c = threadIdx.x;
    __shared__ float xs[2][HH];
    xs[0][c] = x[r0 * HH + c];
    xs[1][c] = x[(r0 + 1) * HH + c];
    __syncthreads();
    float aq[2], ak[2], av[2];
    #pragma unroll
    for (int r = 0; r < 2; ++r) { aq[r] = bq[c]; ak[r] = bk[c]; av[r] = bv[c]; }
    #pragma unroll 4
    for (int i = 0; i < HH; ++i) {
        const float wq = Wq[i * HH + c];
        const float wk = Wk[i * HH + c];
        const float wv = Wv[i * HH + c];
        #pragma unroll
        for (int r = 0; r < 2; ++r) {
            const float xv = xs[r][i];
            aq[r] = fmaf(xv, wq, aq[r]);
            ak[r] = fmaf(xv, wk, ak[r]);
            av[r] = fmaf(xv, wv, av[r]);
        }
    }
    #pragma unroll
    for (int r = 0; r < 2; ++r) {
        const int idx = (r0 + r) * HH + c;
        q[idx]  = aq[r];
        kp[idx] = ak[r] + abs_pos_k[idx];
        vp[idx] = av[r] + abs_pos_v[idx];
    }
}

// K2: flash-style half-row attention. grid = BB*LL*2.
// Phases 1/3 use explicit batch-16 load-then-compute: all loads of an
// 8-iteration chunk are issued before any consumer, guaranteeing deep
// VMEM pipelining per wave regardless of compiler hoisting.
//   t = kis*32 + c4 ; h = c4>>2.
__global__ __launch_bounds__(256) void attn_flash_kernel(
    const float* __restrict__ q,
    const float* __restrict__ kp,
    const float* __restrict__ vp,
    const float* __restrict__ time_k,
    const float* __restrict__ time_v,
    const float* __restrict__ mask,
    float* __restrict__ pctx,     // [2][BB*LL][HH] raw (unnormalized)
    float2* __restrict__ msbuf)   // [2][BB*LL][NH] {max, expsum}
{
    const int half = blockIdx.x & 1;
    const int row  = blockIdx.x >> 1;
    const int b    = row >> 9;
    const int t    = threadIdx.x;
    const int c4   = t & 31;
    const int kis  = t >> 5;
    const int h    = c4 >> 2;

    __shared__ float s_q[HH];
    __shared__ float s_p[KHALF * SP_STRIDE];  // 256 ki x 8 h, pad 9 (9.2 KB)
    __shared__ float s_red[8][HH];            // ctx partials (4 KB)

    if (t < HH) s_q[t] = q[row * HH + t];
    __syncthreads();

    const float4 q4 = ((const float4*)s_q)[c4];
    const f32x4*  __restrict__ tk4 = (const f32x4*)(time_k
        + (size_t)row * (size_t)(LL * HH) + (size_t)half * KHALF * HH);
    const float4* __restrict__ kq4 = (const float4*)(kp
        + (size_t)b * (size_t)(LL * HH) + (size_t)half * KHALF * HH);

    // ---- phase 1: raw scores, chunks of 8 kb-iterations (16 loads in flight)
    for (int kb0 = 0; kb0 < KHALF / 8; kb0 += 8) {
        f32x4  ta[8];
        float4 tb[8];
        #pragma unroll
        for (int j = 0; j < 8; ++j) {
            const int off = ((kb0 + j) * 8 + kis) * 32 + c4;
            ta[j] = __builtin_nontemporal_load(tk4 + off);
            tb[j] = kq4[off];
        }
        #pragma unroll
        for (int j = 0; j < 8; ++j) {
            float part = q4.x * (ta[j].x + tb[j].x) + q4.y * (ta[j].y + tb[j].y)
                       + q4.z * (ta[j].z + tb[j].z) + q4.w * (ta[j].w + tb[j].w);
            part += __shfl_xor(part, 1);
            part += __shfl_xor(part, 2);
            if ((c4 & 3) == 0)
                s_p[((kb0 + j) * 8 + kis) * SP_STRIDE + h] = part;
        }
    }
    __syncthreads();

    // ---- phase 2: LOCAL softmax per head (32 threads/head); scale+mask here.
    {
        const float* __restrict__ mrow = mask + (size_t)row * LL + half * KHALF;
        const int hh  = t >> 5;
        const int l32 = t & 31;
        float v[KHALF / 32];                      // 8
        float m = -1e30f;
        #pragma unroll
        for (int j = 0; j < KHALF / 32; ++j) {
            const int ki = l32 + j * 32;
            v[j] = s_p[ki * SP_STRIDE + hh] * 0.25f + mrow[ki];
            m = fmaxf(m, v[j]);
        }
        #pragma unroll
        for (int off = 16; off; off >>= 1) m = fmaxf(m, __shfl_xor(m, off));
        float sum = 0.f;
        #pragma unroll
        for (int j = 0; j < KHALF / 32; ++j) {
            const float e = __expf(v[j] - m);
            s_p[(l32 + j * 32) * SP_STRIDE + hh] = e;
            sum += e;
        }
        #pragma unroll
        for (int off = 16; off; off >>= 1) sum += __shfl_xor(sum, off);
        if (l32 == 0)
            msbuf[((size_t)half * (BB * LL) + row) * NH + hh] = make_float2(m, sum);
    }
    __syncthreads();

    // ---- phase 3: UNNORMALIZED partial ctx, same batch-16 structure
    const f32x4*  __restrict__ tv4 = (const f32x4*)(time_v
        + (size_t)row * (size_t)(LL * HH) + (size_t)half * KHALF * HH);
    const float4* __restrict__ vq4 = (const float4*)(vp
        + (size_t)b * (size_t)(LL * HH) + (size_t)half * KHALF * HH);
    float4 acc = make_float4(0.f, 0.f, 0.f, 0.f);
    for (int kb0 = 0; kb0 < KHALF / 8; kb0 += 8) {
        f32x4  ta[8];
        float4 tb[8];
        #pragma unroll
        for (int j = 0; j < 8; ++j) {
            const int off = ((kb0 + j) * 8 + kis) * 32 + c4;
            ta[j] = __builtin_nontemporal_load(tv4 + off);
            tb[j] = vq4[off];
        }
        #pragma unroll
        for (int j = 0; j < 8; ++j) {
            const float p = s_p[((kb0 + j) * 8 + kis) * SP_STRIDE + h];
            acc.x = fmaf(p, ta[j].x + tb[j].x, acc.x);
            acc.y = fmaf(p, ta[j].y + tb[j].y, acc.y);
            acc.z = fmaf(p, ta[j].z + tb[j].z, acc.z);
            acc.w = fmaf(p, ta[j].w + tb[j].w, acc.w);
        }
    }
    ((float4*)s_red)[kis * 32 + c4] = acc;
    __syncthreads();

    if (t < HH) {
        float cv = 0.f;
        #pragma unroll
        for (int r = 0; r < 8; ++r) cv += s_red[r][t];
        pctx[(size_t)half * (BB * LL * HH) + (size_t)row * HH + t] = cv;
    }
}

// K3: flash combine of the two halves + out-projection. grid = BB*LL.
__global__ __launch_bounds__(256) void combine_kernel(
    const float* __restrict__ pctx,
    const float2* __restrict__ msbuf,
    const float* __restrict__ Wo,
    const float* __restrict__ bo,
    float* __restrict__ out)
{
    const int row = blockIdx.x;
    const int t   = threadIdx.x;
    __shared__ float s_ctx[HH];
    __shared__ float s_red[2][HH];

    if (t < HH) {
        const int h = t >> 4;                     // 16 dims per head
        const float2 ms0 = msbuf[(size_t)row * NH + h];
        const float2 ms1 = msbuf[(size_t)(BB * LL + row) * NH + h];
        const float M  = fmaxf(ms0.x, ms1.x);
        const float e0 = __expf(ms0.x - M);
        const float e1 = __expf(ms1.x - M);
        const float denom = ms0.y * e0 + ms1.y * e1;
        const float p0 = pctx[(size_t)row * HH + t];
        const float p1 = pctx[(size_t)(BB * LL * HH) + (size_t)row * HH + t];
        s_ctx[t] = (p0 * e0 + p1 * e1) / denom;
    }
    __syncthreads();

    {
        const int to   = t & (HH - 1);
        const int half = t >> 7;
        float o = half ? 0.f : bo[to];
        const int i0 = half * (HH / 2);
        #pragma unroll 4
        for (int i = i0; i < i0 + HH / 2; ++i)
            o = fmaf(s_ctx[i], Wo[i * HH + to], o);
        s_red[half][to] = o;
    }
    __syncthreads();
    if (t < HH)
        out[(size_t)row * HH + t] = s_red[0][t] + s_red[1][t];
}

extern "C" void kernel_launch(void* const* d_in, const int* in_sizes, int n_in,
                              void* d_out, int out_size, void* d_ws, size_t ws_size,
                              hipStream_t stream) {
    const float* x         = (const float*)d_in[0];
    const float* time_k    = (const float*)d_in[1];
    const float* time_v    = (const float*)d_in[2];
    const float* abs_pos_k = (const float*)d_in[3];
    const float* abs_pos_v = (const float*)d_in[4];
    const float* attn_mask = (const float*)d_in[5];
    const float* Wq = (const float*)d_in[6];
    const float* bq = (const float*)d_in[7];
    const float* Wk = (const float*)d_in[8];
    const float* bk = (const float*)d_in[9];
    const float* Wv = (const float*)d_in[10];
    const float* bv = (const float*)d_in[11];
    const float* Wo = (const float*)d_in[12];
    const float* bo = (const float*)d_in[13];
    float* out = (float*)d_out;

    float*  q     = (float*)d_ws;                        // [2*512*128]
    float*  kp    = q  + BB * LL * HH;                   // k + abs_k
    float*  vp    = kp + BB * LL * HH;                   // v + abs_v
    float*  pctx  = vp + BB * LL * HH;                   // [2][1024][128] = 1 MB
    float2* msbuf = (float2*)(pctx + 2 * BB * LL * HH);  // [2][1024][8] = 128 KB

    qkv_proj_kernel<<<BB * LL / 2, 128, 0, stream>>>(
        x, abs_pos_k, abs_pos_v, Wq, bq, Wk, bk, Wv, bv, q, kp, vp);

    attn_flash_kernel<<<BB * LL * 2, 256, 0, stream>>>(
        q, kp, vp, time_k, time_v, attn_mask, pctx, msbuf);

    combine_kernel<<<BB * LL, 256, 0, stream>>>(pctx, msbuf, Wo, bo, out);
}